// Round 5
// baseline (1388.368 us; speedup 1.0000x reference)
//
#include <hip/hip_runtime.h>
#include <math.h>

constexpr int F_IN  = 128;
constexpr int H_MID = 16;
constexpr int C_OUT = 10;

// ---- edge-partition parameters (N < 2^17 = 131072; here N = 100000) ----
constexpr int NB     = 512;   // coarse buckets: bucket = dst >> 8 (256 nodes each)
constexpr int BSH    = 8;
constexpr int CAP_SH = 13;    // 8192 slots per bucket (mean 6250, sigma ~79)

// ---------------- init per-bucket cursors ----------------
__global__ __launch_bounds__(NB) void k_init(int* __restrict__ gcursor) {
  gcursor[threadIdx.x] = threadIdx.x << CAP_SH;
}

// ---------------- direct bucket scatter: epart[pos] = ((dst&255)<<17)|src ----------------
__global__ __launch_bounds__(256) void k_scatter_bucket(
    const int* __restrict__ src, const int* __restrict__ dst,
    int* __restrict__ gcursor, int* __restrict__ epart, int E) {
  int e = blockIdx.x * 256 + threadIdx.x;
  if (e >= E) return;
  const int d = dst[e];
  const int b = d >> BSH;
  const int pos = atomicAdd(&gcursor[b], 1);
  epart[pos] = ((d & ((1 << BSH) - 1)) << 17) | src[e];
}

// ---------------- scan bucket counts (1 block) ----------------
__global__ __launch_bounds__(NB) void k_bscan(const int* __restrict__ gcursor,
                                              int* __restrict__ gbbase,
                                              int* __restrict__ rowptr, int N, int E) {
  __shared__ int sA[NB], sB[NB];
  const int t = threadIdx.x;
  const int cnt = gcursor[t] - (t << CAP_SH);
  sA[t] = cnt;
  __syncthreads();
  int* pa = sA; int* pb = sB;
  for (int off = 1; off < NB; off <<= 1) {
    pb[t] = pa[t] + ((t >= off) ? pa[t - off] : 0);
    __syncthreads();
    int* tmp = pa; pa = pb; pb = tmp;
  }
  gbbase[t] = pa[t] - cnt;  // exclusive
  if (t == NB - 1) { gbbase[NB] = pa[t]; rowptr[N] = E; }
}

// ---------------- per-bucket placement + deg/rowptr/dinv ----------------
__global__ __launch_bounds__(256) void k_place(
    const int* __restrict__ epart, const int* __restrict__ gbbase,
    const int* __restrict__ gcursor,
    int* __restrict__ adj, int* __restrict__ rowptr, float* __restrict__ dinv,
    int N) {
  __shared__ int ldeg[256];
  __shared__ int sA[256], sB[256];
  __shared__ int cur[256];
  const int b = blockIdx.x, t = threadIdx.x;
  const int in0 = b << CAP_SH;
  const int lim = gcursor[b] - in0;      // edges in this bucket
  const int e0  = gbbase[b];             // dense output base
  ldeg[t] = 0;
  __syncthreads();
  for (int i = t; i < lim; i += 256) atomicAdd(&ldeg[epart[in0 + i] >> 17], 1);
  __syncthreads();
  const int myDeg = ldeg[t];
  sA[t] = myDeg;
  __syncthreads();
  int* pa = sA; int* pb = sB;
  for (int off = 1; off < 256; off <<= 1) {
    pb[t] = pa[t] + ((t >= off) ? pa[t - off] : 0);
    __syncthreads();
    int* tmp = pa; pa = pb; pb = tmp;
  }
  const int lbase = pa[t] - myDeg;
  cur[t] = lbase;
  const int node = (b << BSH) + t;
  if (node < N) {
    rowptr[node] = e0 + lbase;
    dinv[node]   = rsqrtf((float)(myDeg + 1));  // +1 self-loop
  }
  __syncthreads();
  for (int i = t; i < lim; i += 256) {
    const int p = epart[in0 + i];
    const int pos = atomicAdd(&cur[p >> 17], 1);
    adj[e0 + pos] = p & 0x1FFFF;
  }
}

// ---------------- m = (x2 @ W1) * dinv[row] ----------------
__global__ __launch_bounds__(256) void k_gemv16(
    const float* __restrict__ x, const float* __restrict__ W,
    const float* __restrict__ dinv, float* __restrict__ m, int N) {
  __shared__ float ws[F_IN * H_MID];   // 8 KB
  __shared__ float xs[64 * 132];       // pad 128->132
  const int t = threadIdx.x;
  for (int i = t; i < F_IN * H_MID; i += 256) ws[i] = W[i];
  const int row0 = blockIdx.x * 64;
  const int rows = min(64, N - row0);
  const float4* xg = (const float4*)(x + (size_t)row0 * F_IN);
  for (int i = t; i < rows * 32; i += 256) {
    int rl = i >> 5, c = i & 31;
    float4 v = xg[rl * 32 + c];
    *(float4*)&xs[rl * 132 + c * 4] = v;
  }
  __syncthreads();
  const int rl = t >> 2;
  const int j0 = (t & 3) * 4;
  if (rl < rows) {
    float a0 = 0.f, a1 = 0.f, a2 = 0.f, a3 = 0.f;
    const float* xr = &xs[rl * 132];
    #pragma unroll
    for (int k = 0; k < F_IN; ++k) {
      const float xv = xr[k];
      const float* wr = &ws[k * H_MID + j0];
      a0 = fmaf(xv, wr[0], a0);
      a1 = fmaf(xv, wr[1], a1);
      a2 = fmaf(xv, wr[2], a2);
      a3 = fmaf(xv, wr[3], a3);
    }
    const int row = row0 + rl;
    const float dv = dinv[row];
    *(float4*)&m[(size_t)row * H_MID + j0] =
        make_float4(a0 * dv, a1 * dv, a2 * dv, a3 * dv);
  }
}

// ---------------- gather 16 feats: 4 threads/node, float4 each ----------------
__global__ void k_gather16(const float* __restrict__ m, const int* __restrict__ rowptr,
                           const int* __restrict__ adj, float* __restrict__ agg, int N) {
  const int t = blockIdx.x * 256 + threadIdx.x;
  const int n = t >> 2, q = t & 3;
  if (n >= N) return;
  const float4* M4 = (const float4*)m;
  const int beg = rowptr[n], end = rowptr[n + 1];
  float4 s = M4[n * 4 + q];  // self-loop
  int k = beg;
  for (; k + 4 <= end; k += 4) {
    const int s0 = adj[k], s1 = adj[k + 1], s2 = adj[k + 2], s3 = adj[k + 3];
    const float4 a = M4[s0 * 4 + q];
    const float4 b = M4[s1 * 4 + q];
    const float4 c = M4[s2 * 4 + q];
    const float4 d = M4[s3 * 4 + q];
    s.x += (a.x + b.x) + (c.x + d.x);
    s.y += (a.y + b.y) + (c.y + d.y);
    s.z += (a.z + b.z) + (c.z + d.z);
    s.w += (a.w + b.w) + (c.w + d.w);
  }
  for (; k < end; ++k) {
    const float4 a = M4[adj[k] * 4 + q];
    s.x += a.x; s.y += a.y; s.z += a.z; s.w += a.w;
  }
  ((float4*)agg)[t] = s;
}

// ---------------- h2 = relu(hg*dinv + b1); hg <- (h2 @ Wend)*dinv ----------------
__global__ __launch_bounds__(256) void k_mid(
    float* hg, const float* __restrict__ dinv,
    const float* __restrict__ b1, const float* __restrict__ Wend, int N) {
  __shared__ float ws[H_MID * C_OUT];
  __shared__ float bs[H_MID];
  const int t = threadIdx.x;
  if (t < H_MID * C_OUT) ws[t] = Wend[t];
  if (t < H_MID) bs[t] = b1[t];
  __syncthreads();
  const int n = blockIdx.x * 256 + t;
  if (n >= N) return;
  const float dv = dinv[n];
  float h[H_MID];
  const float4* ag = (const float4*)(hg + (size_t)n * H_MID);
  #pragma unroll
  for (int q = 0; q < 4; ++q) {
    float4 v = ag[q];
    h[4*q+0] = fmaxf(fmaf(v.x, dv, bs[4*q+0]), 0.f);
    h[4*q+1] = fmaxf(fmaf(v.y, dv, bs[4*q+1]), 0.f);
    h[4*q+2] = fmaxf(fmaf(v.z, dv, bs[4*q+2]), 0.f);
    h[4*q+3] = fmaxf(fmaf(v.w, dv, bs[4*q+3]), 0.f);
  }
  float o[C_OUT];
  #pragma unroll
  for (int jj = 0; jj < C_OUT; ++jj) {
    float a = 0.f;
    #pragma unroll
    for (int k = 0; k < H_MID; ++k) a = fmaf(h[k], ws[k * C_OUT + jj], a);
    o[jj] = a * dv;
  }
  float2* gp = (float2*)(hg + (size_t)n * H_MID);
  #pragma unroll
  for (int q = 0; q < 5; ++q) gp[q] = make_float2(o[2*q], o[2*q+1]);
}

// ---------------- gather 10 feats + bias + log_softmax ----------------
__global__ void k_gather10_final(const float* __restrict__ hg, const int* __restrict__ rowptr,
                                 const int* __restrict__ adj, const float* __restrict__ dinv,
                                 const float* __restrict__ bend, float* __restrict__ out, int N) {
  int t = blockIdx.x * 256 + threadIdx.x;
  int n = t >> 4, j = t & 15;
  if (n >= N) return;
  float s = 0.f;
  if (j < C_OUT) {
    int beg = rowptr[n], end = rowptr[n + 1];
    s = hg[(size_t)n * 16 + j];  // self-loop
    int k = beg;
    for (; k + 4 <= end; k += 4) {
      int s0 = adj[k], s1 = adj[k + 1], s2 = adj[k + 2], s3 = adj[k + 3];
      float a = hg[(size_t)s0 * 16 + j];
      float b = hg[(size_t)s1 * 16 + j];
      float c = hg[(size_t)s2 * 16 + j];
      float d = hg[(size_t)s3 * 16 + j];
      s += (a + b) + (c + d);
    }
    for (; k < end; ++k) s += hg[(size_t)adj[k] * 16 + j];
  }
  float v = (j < C_OUT) ? fmaf(s, dinv[n], bend[j]) : -INFINITY;
  float mx = v;
  #pragma unroll
  for (int w = 8; w; w >>= 1) mx = fmaxf(mx, __shfl_xor(mx, w, 16));
  float e = (j < C_OUT) ? __expf(v - mx) : 0.f;
  float ss = e;
  #pragma unroll
  for (int w = 8; w; w >>= 1) ss += __shfl_xor(ss, w, 16);
  if (j < C_OUT) out[(size_t)n * C_OUT + j] = v - (__logf(ss) + mx);
}

extern "C" void kernel_launch(void* const* d_in, const int* in_sizes, int n_in,
                              void* d_out, int out_size, void* d_ws, size_t ws_size,
                              hipStream_t stream) {
  // inputs: 0=x1 1=x2 2=W1 3=b1 4=W_end 5=b_end 6=edge_index1 7=edge_index2 8=skip
  // x1 / edge_index1 / skip are dead w.r.t. the returned output.
  const float* x2   = (const float*)d_in[1];
  const float* W1   = (const float*)d_in[2];
  const float* b1   = (const float*)d_in[3];
  const float* Wend = (const float*)d_in[4];
  const float* bend = (const float*)d_in[5];
  const int*   ei2  = (const int*)d_in[7];
  const int N = in_sizes[1] / F_IN;
  const int E = in_sizes[7] / 2;
  const int* src = ei2;
  const int* dst = ei2 + E;

  char* base = (char*)d_ws;
  size_t off = 0;
  auto alloc = [&](size_t bytes) -> void* {
    void* p = (void*)(base + off);
    off += ((bytes + 255) / 256) * 256;
    return p;
  };
  int*   gcursor = (int*)  alloc((size_t)NB * 4);
  int*   gbbase  = (int*)  alloc(((size_t)NB + 1) * 4);
  int*   rowptr  = (int*)  alloc(((size_t)N + 1) * 4);
  float* dinv    = (float*)alloc((size_t)N * 4);
  int*   adj     = (int*)  alloc((size_t)E * 4);
  // region A: epart (NB<<CAP_SH ints = 16.8 MB) early; m+agg (12.8 MB) later.
  char*  regA    = (char*) alloc(((size_t)NB << CAP_SH) * 4);
  int*   epart   = (int*)  regA;
  float* m       = (float*)regA;
  float* agg     = (float*)(regA + (size_t)N * H_MID * 4);

  const dim3 blk(256);
  const int gN  = (N + 255) / 256;
  const int gE  = (E + 255) / 256;
  const int gNB = (N + 255) >> BSH;       // buckets covering nodes (391)
  const int gNF = ((N * 16) + 255) / 256;
  const int gN4 = ((N * 4) + 255) / 256;

  hipLaunchKernelGGL(k_init,           dim3(1),   dim3(NB), 0, stream, gcursor);
  hipLaunchKernelGGL(k_scatter_bucket, dim3(gE),  blk, 0, stream, src, dst, gcursor, epart, E);
  hipLaunchKernelGGL(k_bscan,          dim3(1),   dim3(NB), 0, stream, gcursor, gbbase, rowptr, N, E);
  hipLaunchKernelGGL(k_place,          dim3(gNB), blk, 0, stream, epart, gbbase, gcursor, adj, rowptr, dinv, N);
  hipLaunchKernelGGL(k_gemv16,         dim3((N + 63) / 64), blk, 0, stream, x2, W1, dinv, m, N);
  hipLaunchKernelGGL(k_gather16,       dim3(gN4), blk, 0, stream, m, rowptr, adj, agg, N);
  hipLaunchKernelGGL(k_mid,            dim3(gN),  blk, 0, stream, agg, dinv, b1, Wend, N);
  hipLaunchKernelGGL(k_gather10_final, dim3(gNF), blk, 0, stream,
                     agg, rowptr, adj, dinv, bend, (float*)d_out, N);
}

// Round 6
// 354.497 us; speedup vs baseline: 3.9164x; 3.9164x over previous
//
#include <hip/hip_runtime.h>
#include <math.h>

constexpr int F_IN  = 128;
constexpr int H_MID = 16;
constexpr int C_OUT = 10;

// ---- edge-partition parameters (N < 2^17 = 131072; here N = 100000) ----
constexpr int NB     = 512;   // coarse buckets: bucket = dst >> 8 (256 nodes each)
constexpr int BSH    = 8;
constexpr int CAP_SH = 13;    // 8192 slots per bucket (mean 6250, sigma ~79)
constexpr int CHUNK  = 4096;  // edges per partition block

// ---------------- init per-bucket cursors ----------------
__global__ __launch_bounds__(NB) void k_init(int* __restrict__ gcursor) {
  gcursor[threadIdx.x] = threadIdx.x << CAP_SH;
}

// ---------------- two-pass LDS-aggregated bucket partition ----------------
// Global atomics: <= 1 per (block, bucket) pair (782*512 max, ~782 per counter).
// epart writes land in block-exclusive reserved runs -> no cross-XCD line sharing.
__global__ __launch_bounds__(256) void k_partition2(
    const int* __restrict__ src, const int* __restrict__ dst,
    int* __restrict__ gcursor, int* __restrict__ epart, int E) {
  __shared__ int hist[NB];   // counts, then local cursor
  __shared__ int gbase[NB];  // reserved global base per bucket
  const int t = threadIdx.x;
  const int base = blockIdx.x * CHUNK;
  const int lim  = min(CHUNK, E - base);
  for (int i = t; i < NB; i += 256) hist[i] = 0;
  __syncthreads();
  for (int i = t; i < lim; i += 256) atomicAdd(&hist[dst[base + i] >> BSH], 1);
  __syncthreads();
  for (int b = t; b < NB; b += 256) {
    const int cnt = hist[b];
    gbase[b] = cnt ? atomicAdd(&gcursor[b], cnt) : 0;
    hist[b] = 0;  // reuse as local cursor
  }
  __syncthreads();
  for (int i = t; i < lim; i += 256) {
    const int d = dst[base + i];
    const int b = d >> BSH;
    const int loc = atomicAdd(&hist[b], 1);
    epart[gbase[b] + loc] = ((d & ((1 << BSH) - 1)) << 17) | src[base + i];
  }
}

// ---------------- scan bucket counts (1 block) ----------------
__global__ __launch_bounds__(NB) void k_bscan(const int* __restrict__ gcursor,
                                              int* __restrict__ gbbase,
                                              int* __restrict__ rowptr, int N, int E) {
  __shared__ int sA[NB], sB[NB];
  const int t = threadIdx.x;
  const int cnt = gcursor[t] - (t << CAP_SH);
  sA[t] = cnt;
  __syncthreads();
  int* pa = sA; int* pb = sB;
  for (int off = 1; off < NB; off <<= 1) {
    pb[t] = pa[t] + ((t >= off) ? pa[t - off] : 0);
    __syncthreads();
    int* tmp = pa; pa = pb; pb = tmp;
  }
  gbbase[t] = pa[t] - cnt;  // exclusive
  if (t == NB - 1) { gbbase[NB] = pa[t]; rowptr[N] = E; }
}

// ---------------- per-bucket placement + deg/rowptr/dinv ----------------
__global__ __launch_bounds__(256) void k_place(
    const int* __restrict__ epart, const int* __restrict__ gbbase,
    const int* __restrict__ gcursor,
    int* __restrict__ adj, int* __restrict__ rowptr, float* __restrict__ dinv,
    int N) {
  __shared__ int ldeg[256];
  __shared__ int sA[256], sB[256];
  __shared__ int cur[256];
  const int b = blockIdx.x, t = threadIdx.x;
  const int in0 = b << CAP_SH;
  const int lim = gcursor[b] - in0;      // edges in this bucket
  const int e0  = gbbase[b];             // dense output base
  ldeg[t] = 0;
  __syncthreads();
  for (int i = t; i < lim; i += 256) atomicAdd(&ldeg[epart[in0 + i] >> 17], 1);
  __syncthreads();
  const int myDeg = ldeg[t];
  sA[t] = myDeg;
  __syncthreads();
  int* pa = sA; int* pb = sB;
  for (int off = 1; off < 256; off <<= 1) {
    pb[t] = pa[t] + ((t >= off) ? pa[t - off] : 0);
    __syncthreads();
    int* tmp = pa; pa = pb; pb = tmp;
  }
  const int lbase = pa[t] - myDeg;
  cur[t] = lbase;
  const int node = (b << BSH) + t;
  if (node < N) {
    rowptr[node] = e0 + lbase;
    dinv[node]   = rsqrtf((float)(myDeg + 1));  // +1 self-loop
  }
  __syncthreads();
  for (int i = t; i < lim; i += 256) {
    const int p = epart[in0 + i];
    const int pos = atomicAdd(&cur[p >> 17], 1);
    adj[e0 + pos] = p & 0x1FFFF;
  }
}

// ---------------- m = (x2 @ W1) * dinv[row] ----------------
__global__ __launch_bounds__(256) void k_gemv16(
    const float* __restrict__ x, const float* __restrict__ W,
    const float* __restrict__ dinv, float* __restrict__ m, int N) {
  __shared__ float ws[F_IN * H_MID];   // 8 KB
  __shared__ float xs[64 * 132];       // pad 128->132
  const int t = threadIdx.x;
  for (int i = t; i < F_IN * H_MID; i += 256) ws[i] = W[i];
  const int row0 = blockIdx.x * 64;
  const int rows = min(64, N - row0);
  const float4* xg = (const float4*)(x + (size_t)row0 * F_IN);
  for (int i = t; i < rows * 32; i += 256) {
    int rl = i >> 5, c = i & 31;
    float4 v = xg[rl * 32 + c];
    *(float4*)&xs[rl * 132 + c * 4] = v;
  }
  __syncthreads();
  const int rl = t >> 2;
  const int j0 = (t & 3) * 4;
  if (rl < rows) {
    float a0 = 0.f, a1 = 0.f, a2 = 0.f, a3 = 0.f;
    const float* xr = &xs[rl * 132];
    #pragma unroll
    for (int k = 0; k < F_IN; ++k) {
      const float xv = xr[k];
      const float* wr = &ws[k * H_MID + j0];
      a0 = fmaf(xv, wr[0], a0);
      a1 = fmaf(xv, wr[1], a1);
      a2 = fmaf(xv, wr[2], a2);
      a3 = fmaf(xv, wr[3], a3);
    }
    const int row = row0 + rl;
    const float dv = dinv[row];
    *(float4*)&m[(size_t)row * H_MID + j0] =
        make_float4(a0 * dv, a1 * dv, a2 * dv, a3 * dv);
  }
}

// ---------------- fused: gather16 + (relu/b1) + Wend GEMV + dinv scale ----------------
// 4 threads/node, float4 each; h exchanged through LDS; g written in [N][16] layout.
__global__ __launch_bounds__(256) void k_gather16_mid(
    const float* __restrict__ m, const int* __restrict__ rowptr,
    const int* __restrict__ adj, const float* __restrict__ dinv,
    const float* __restrict__ b1, const float* __restrict__ Wend,
    float* __restrict__ g, int N) {
  __shared__ float ws[H_MID * C_OUT];   // 160
  __shared__ float bs[H_MID];
  __shared__ float hs[64][H_MID + 1];   // pad 17 -> conflict-free
  const int t = threadIdx.x;
  if (t < H_MID * C_OUT) ws[t] = Wend[t];
  if (t < H_MID) bs[t] = b1[t];
  const int nl = t >> 2, q = t & 3;
  const int n = blockIdx.x * 64 + nl;
  float4 s = make_float4(0.f, 0.f, 0.f, 0.f);
  float dv = 0.f;
  if (n < N) {
    const float4* M4 = (const float4*)m;
    const int beg = rowptr[n], end = rowptr[n + 1];
    s = M4[n * 4 + q];  // self-loop
    int k = beg;
    for (; k + 4 <= end; k += 4) {
      const int s0 = adj[k], s1 = adj[k + 1], s2 = adj[k + 2], s3 = adj[k + 3];
      const float4 a = M4[s0 * 4 + q];
      const float4 b = M4[s1 * 4 + q];
      const float4 c = M4[s2 * 4 + q];
      const float4 d = M4[s3 * 4 + q];
      s.x += (a.x + b.x) + (c.x + d.x);
      s.y += (a.y + b.y) + (c.y + d.y);
      s.z += (a.z + b.z) + (c.z + d.z);
      s.w += (a.w + b.w) + (c.w + d.w);
    }
    for (; k < end; ++k) {
      const float4 a = M4[adj[k] * 4 + q];
      s.x += a.x; s.y += a.y; s.z += a.z; s.w += a.w;
    }
    dv = dinv[n];
  }
  __syncthreads();  // ws/bs visible
  if (n < N) {
    const int j0 = q * 4;
    hs[nl][j0 + 0] = fmaxf(fmaf(s.x, dv, bs[j0 + 0]), 0.f);
    hs[nl][j0 + 1] = fmaxf(fmaf(s.y, dv, bs[j0 + 1]), 0.f);
    hs[nl][j0 + 2] = fmaxf(fmaf(s.z, dv, bs[j0 + 2]), 0.f);
    hs[nl][j0 + 3] = fmaxf(fmaf(s.w, dv, bs[j0 + 3]), 0.f);
  }
  __syncthreads();
  if (n < N) {
    // outputs j = q, q+4, q+8 (q<2 only for +8): covers 0..9
    float o0 = 0.f, o1 = 0.f, o2 = 0.f;
    const float* hr = hs[nl];
    #pragma unroll
    for (int k = 0; k < H_MID; ++k) {
      const float hv = hr[k];
      o0 = fmaf(hv, ws[k * C_OUT + q], o0);
      o1 = fmaf(hv, ws[k * C_OUT + q + 4], o1);
      if (q < 2) o2 = fmaf(hv, ws[k * C_OUT + q + 8], o2);
    }
    float* gr = g + (size_t)n * H_MID;
    gr[q]     = o0 * dv;
    gr[q + 4] = o1 * dv;
    if (q < 2) gr[q + 8] = o2 * dv;
  }
}

// ---------------- gather 10 feats + bias + log_softmax ----------------
__global__ void k_gather10_final(const float* __restrict__ hg, const int* __restrict__ rowptr,
                                 const int* __restrict__ adj, const float* __restrict__ dinv,
                                 const float* __restrict__ bend, float* __restrict__ out, int N) {
  int t = blockIdx.x * 256 + threadIdx.x;
  int n = t >> 4, j = t & 15;
  if (n >= N) return;
  float s = 0.f;
  if (j < C_OUT) {
    int beg = rowptr[n], end = rowptr[n + 1];
    s = hg[(size_t)n * 16 + j];  // self-loop
    int k = beg;
    for (; k + 4 <= end; k += 4) {
      int s0 = adj[k], s1 = adj[k + 1], s2 = adj[k + 2], s3 = adj[k + 3];
      float a = hg[(size_t)s0 * 16 + j];
      float b = hg[(size_t)s1 * 16 + j];
      float c = hg[(size_t)s2 * 16 + j];
      float d = hg[(size_t)s3 * 16 + j];
      s += (a + b) + (c + d);
    }
    for (; k < end; ++k) s += hg[(size_t)adj[k] * 16 + j];
  }
  float v = (j < C_OUT) ? fmaf(s, dinv[n], bend[j]) : -INFINITY;
  float mx = v;
  #pragma unroll
  for (int w = 8; w; w >>= 1) mx = fmaxf(mx, __shfl_xor(mx, w, 16));
  float e = (j < C_OUT) ? __expf(v - mx) : 0.f;
  float ss = e;
  #pragma unroll
  for (int w = 8; w; w >>= 1) ss += __shfl_xor(ss, w, 16);
  if (j < C_OUT) out[(size_t)n * C_OUT + j] = v - (__logf(ss) + mx);
}

extern "C" void kernel_launch(void* const* d_in, const int* in_sizes, int n_in,
                              void* d_out, int out_size, void* d_ws, size_t ws_size,
                              hipStream_t stream) {
  // inputs: 0=x1 1=x2 2=W1 3=b1 4=W_end 5=b_end 6=edge_index1 7=edge_index2 8=skip
  // x1 / edge_index1 / skip are dead w.r.t. the returned output.
  const float* x2   = (const float*)d_in[1];
  const float* W1   = (const float*)d_in[2];
  const float* b1   = (const float*)d_in[3];
  const float* Wend = (const float*)d_in[4];
  const float* bend = (const float*)d_in[5];
  const int*   ei2  = (const int*)d_in[7];
  const int N = in_sizes[1] / F_IN;
  const int E = in_sizes[7] / 2;
  const int* src = ei2;
  const int* dst = ei2 + E;

  char* base = (char*)d_ws;
  size_t off = 0;
  auto alloc = [&](size_t bytes) -> void* {
    void* p = (void*)(base + off);
    off += ((bytes + 255) / 256) * 256;
    return p;
  };
  int*   gcursor = (int*)  alloc((size_t)NB * 4);
  int*   gbbase  = (int*)  alloc(((size_t)NB + 1) * 4);
  int*   rowptr  = (int*)  alloc(((size_t)N + 1) * 4);
  float* dinv    = (float*)alloc((size_t)N * 4);
  int*   adj     = (int*)  alloc((size_t)E * 4);
  // region A: epart (NB<<CAP_SH ints = 16.8 MB) early; m+g (12.8 MB) later.
  char*  regA    = (char*) alloc(((size_t)NB << CAP_SH) * 4);
  int*   epart   = (int*)  regA;
  float* m       = (float*)regA;
  float* g       = (float*)(regA + (size_t)N * H_MID * 4);

  const dim3 blk(256);
  const int gEC = (E + CHUNK - 1) / CHUNK;   // 782
  const int gNB = (N + 255) >> BSH;          // 391
  const int gNF = ((N * 16) + 255) / 256;
  const int gG  = (N + 63) / 64;             // 1563

  hipLaunchKernelGGL(k_init,           dim3(1),   dim3(NB), 0, stream, gcursor);
  hipLaunchKernelGGL(k_partition2,     dim3(gEC), blk, 0, stream, src, dst, gcursor, epart, E);
  hipLaunchKernelGGL(k_bscan,          dim3(1),   dim3(NB), 0, stream, gcursor, gbbase, rowptr, N, E);
  hipLaunchKernelGGL(k_place,          dim3(gNB), blk, 0, stream, epart, gbbase, gcursor, adj, rowptr, dinv, N);
  hipLaunchKernelGGL(k_gemv16,         dim3(gG),  blk, 0, stream, x2, W1, dinv, m, N);
  hipLaunchKernelGGL(k_gather16_mid,   dim3(gG),  blk, 0, stream, m, rowptr, adj, dinv, b1, Wend, g, N);
  hipLaunchKernelGGL(k_gather10_final, dim3(gNF), blk, 0, stream,
                     g, rowptr, adj, dinv, bend, (float*)d_out, N);
}

// Round 7
// 334.060 us; speedup vs baseline: 4.1560x; 1.0612x over previous
//
#include <hip/hip_runtime.h>
#include <math.h>

constexpr int F_IN  = 128;
constexpr int H_MID = 16;
constexpr int C_OUT = 10;

// ---- edge-partition parameters (N < 2^17 = 131072; here N = 100000) ----
constexpr int NB     = 512;    // coarse buckets: bucket = dst >> 8 (256 nodes each)
constexpr int BSH    = 8;
constexpr int CAP_SH = 13;     // 8192 slots per bucket (mean 6250, sigma ~79)
constexpr int CHUNK  = 16384;  // edges per partition block (runs ~32 edges = 128 B)
constexpr int NXCD   = 8;

// ---------------- init per-bucket cursors ----------------
__global__ __launch_bounds__(NB) void k_init(int* __restrict__ gcursor) {
  gcursor[threadIdx.x] = threadIdx.x << CAP_SH;
}

// ---------------- two-pass LDS-aggregated bucket partition ----------------
// Global atomics: <= 1 per (block, bucket). Chunk order is XCD-swizzled so
// consecutive chunks (adjacent reserved runs sharing boundary cache lines)
// are processed on the SAME XCD -> boundary lines stay in one L2.
__global__ __launch_bounds__(512) void k_partition2(
    const int* __restrict__ src, const int* __restrict__ dst,
    int* __restrict__ gcursor, int* __restrict__ epart, int E, int nwg) {
  __shared__ int hist[NB];   // counts, then local cursor
  __shared__ int gbase[NB];  // reserved global base per bucket
  const int t = threadIdx.x;
  // bijective XCD swizzle (m204): consecutive chunks -> same XCD
  const int orig = blockIdx.x;
  const int q = nwg / NXCD, r = nwg % NXCD;
  const int xcd = orig % NXCD;
  const int chunk = (xcd < r ? xcd * (q + 1) : r * (q + 1) + (xcd - r) * q) + orig / NXCD;
  const int base = chunk * CHUNK;
  const int lim  = min(CHUNK, E - base);
  for (int i = t; i < NB; i += 512) hist[i] = 0;
  __syncthreads();
  for (int i = t; i < lim; i += 512) atomicAdd(&hist[dst[base + i] >> BSH], 1);
  __syncthreads();
  for (int b = t; b < NB; b += 512) {
    const int cnt = hist[b];
    gbase[b] = cnt ? atomicAdd(&gcursor[b], cnt) : 0;
    hist[b] = 0;  // reuse as local cursor
  }
  __syncthreads();
  for (int i = t; i < lim; i += 512) {
    const int d = dst[base + i];
    const int b = d >> BSH;
    const int loc = atomicAdd(&hist[b], 1);
    epart[gbase[b] + loc] = ((d & ((1 << BSH) - 1)) << 17) | src[base + i];
  }
}

// ---------------- scan bucket counts (1 block) ----------------
__global__ __launch_bounds__(NB) void k_bscan(const int* __restrict__ gcursor,
                                              int* __restrict__ gbbase,
                                              int* __restrict__ rowptr, int N, int E) {
  __shared__ int sA[NB], sB[NB];
  const int t = threadIdx.x;
  const int cnt = gcursor[t] - (t << CAP_SH);
  sA[t] = cnt;
  __syncthreads();
  int* pa = sA; int* pb = sB;
  for (int off = 1; off < NB; off <<= 1) {
    pb[t] = pa[t] + ((t >= off) ? pa[t - off] : 0);
    __syncthreads();
    int* tmp = pa; pa = pb; pb = tmp;
  }
  gbbase[t] = pa[t] - cnt;  // exclusive
  if (t == NB - 1) { gbbase[NB] = pa[t]; rowptr[N] = E; }
}

// ---------------- per-bucket placement + deg/rowptr/dinv ----------------
__global__ __launch_bounds__(256) void k_place(
    const int* __restrict__ epart, const int* __restrict__ gbbase,
    const int* __restrict__ gcursor,
    int* __restrict__ adj, int* __restrict__ rowptr, float* __restrict__ dinv,
    int N) {
  __shared__ int ldeg[256];
  __shared__ int sA[256], sB[256];
  __shared__ int cur[256];
  const int b = blockIdx.x, t = threadIdx.x;
  const int in0 = b << CAP_SH;
  const int lim = gcursor[b] - in0;      // edges in this bucket
  const int e0  = gbbase[b];             // dense output base
  ldeg[t] = 0;
  __syncthreads();
  for (int i = t; i < lim; i += 256) atomicAdd(&ldeg[epart[in0 + i] >> 17], 1);
  __syncthreads();
  const int myDeg = ldeg[t];
  sA[t] = myDeg;
  __syncthreads();
  int* pa = sA; int* pb = sB;
  for (int off = 1; off < 256; off <<= 1) {
    pb[t] = pa[t] + ((t >= off) ? pa[t - off] : 0);
    __syncthreads();
    int* tmp = pa; pa = pb; pb = tmp;
  }
  const int lbase = pa[t] - myDeg;
  cur[t] = lbase;
  const int node = (b << BSH) + t;
  if (node < N) {
    rowptr[node] = e0 + lbase;
    dinv[node]   = rsqrtf((float)(myDeg + 1));  // +1 self-loop
  }
  __syncthreads();
  for (int i = t; i < lim; i += 256) {
    const int p = epart[in0 + i];
    const int pos = atomicAdd(&cur[p >> 17], 1);
    adj[e0 + pos] = p & 0x1FFFF;
  }
}

// ---------------- m = (x2 @ W1) * dinv[row] ----------------
__global__ __launch_bounds__(256) void k_gemv16(
    const float* __restrict__ x, const float* __restrict__ W,
    const float* __restrict__ dinv, float* __restrict__ m, int N) {
  __shared__ float ws[F_IN * H_MID];   // 8 KB
  __shared__ float xs[64 * 132];       // pad 128->132
  const int t = threadIdx.x;
  for (int i = t; i < F_IN * H_MID; i += 256) ws[i] = W[i];
  const int row0 = blockIdx.x * 64;
  const int rows = min(64, N - row0);
  const float4* xg = (const float4*)(x + (size_t)row0 * F_IN);
  for (int i = t; i < rows * 32; i += 256) {
    int rl = i >> 5, c = i & 31;
    float4 v = xg[rl * 32 + c];
    *(float4*)&xs[rl * 132 + c * 4] = v;
  }
  __syncthreads();
  const int rl = t >> 2;
  const int j0 = (t & 3) * 4;
  if (rl < rows) {
    float a0 = 0.f, a1 = 0.f, a2 = 0.f, a3 = 0.f;
    const float* xr = &xs[rl * 132];
    #pragma unroll
    for (int k = 0; k < F_IN; ++k) {
      const float xv = xr[k];
      const float* wr = &ws[k * H_MID + j0];
      a0 = fmaf(xv, wr[0], a0);
      a1 = fmaf(xv, wr[1], a1);
      a2 = fmaf(xv, wr[2], a2);
      a3 = fmaf(xv, wr[3], a3);
    }
    const int row = row0 + rl;
    const float dv = dinv[row];
    *(float4*)&m[(size_t)row * H_MID + j0] =
        make_float4(a0 * dv, a1 * dv, a2 * dv, a3 * dv);
  }
}

// ---------------- fused: gather16 + (relu/b1) + Wend GEMV + dinv scale ----------------
// 4 threads/node, float4 each; h exchanged through LDS; g written in [N][16] layout.
__global__ __launch_bounds__(256) void k_gather16_mid(
    const float* __restrict__ m, const int* __restrict__ rowptr,
    const int* __restrict__ adj, const float* __restrict__ dinv,
    const float* __restrict__ b1, const float* __restrict__ Wend,
    float* __restrict__ g, int N) {
  __shared__ float ws[H_MID * C_OUT];   // 160
  __shared__ float bs[H_MID];
  __shared__ float hs[64][H_MID + 1];   // pad 17 -> conflict-free
  const int t = threadIdx.x;
  if (t < H_MID * C_OUT) ws[t] = Wend[t];
  if (t < H_MID) bs[t] = b1[t];
  const int nl = t >> 2, q = t & 3;
  const int n = blockIdx.x * 64 + nl;
  float4 s = make_float4(0.f, 0.f, 0.f, 0.f);
  float dv = 0.f;
  if (n < N) {
    const float4* M4 = (const float4*)m;
    const int beg = rowptr[n], end = rowptr[n + 1];
    s = M4[n * 4 + q];  // self-loop
    int k = beg;
    for (; k + 4 <= end; k += 4) {
      const int s0 = adj[k], s1 = adj[k + 1], s2 = adj[k + 2], s3 = adj[k + 3];
      const float4 a = M4[s0 * 4 + q];
      const float4 b = M4[s1 * 4 + q];
      const float4 c = M4[s2 * 4 + q];
      const float4 d = M4[s3 * 4 + q];
      s.x += (a.x + b.x) + (c.x + d.x);
      s.y += (a.y + b.y) + (c.y + d.y);
      s.z += (a.z + b.z) + (c.z + d.z);
      s.w += (a.w + b.w) + (c.w + d.w);
    }
    for (; k < end; ++k) {
      const float4 a = M4[adj[k] * 4 + q];
      s.x += a.x; s.y += a.y; s.z += a.z; s.w += a.w;
    }
    dv = dinv[n];
  }
  __syncthreads();  // ws/bs visible
  if (n < N) {
    const int j0 = q * 4;
    hs[nl][j0 + 0] = fmaxf(fmaf(s.x, dv, bs[j0 + 0]), 0.f);
    hs[nl][j0 + 1] = fmaxf(fmaf(s.y, dv, bs[j0 + 1]), 0.f);
    hs[nl][j0 + 2] = fmaxf(fmaf(s.z, dv, bs[j0 + 2]), 0.f);
    hs[nl][j0 + 3] = fmaxf(fmaf(s.w, dv, bs[j0 + 3]), 0.f);
  }
  __syncthreads();
  if (n < N) {
    // outputs j = q, q+4, q+8 (q<2 only for +8): covers 0..9
    float o0 = 0.f, o1 = 0.f, o2 = 0.f;
    const float* hr = hs[nl];
    #pragma unroll
    for (int k = 0; k < H_MID; ++k) {
      const float hv = hr[k];
      o0 = fmaf(hv, ws[k * C_OUT + q], o0);
      o1 = fmaf(hv, ws[k * C_OUT + q + 4], o1);
      if (q < 2) o2 = fmaf(hv, ws[k * C_OUT + q + 8], o2);
    }
    float* gr = g + (size_t)n * H_MID;
    gr[q]     = o0 * dv;
    gr[q + 4] = o1 * dv;
    if (q < 2) gr[q + 8] = o2 * dv;
  }
}

// ---------------- gather 10 feats + bias + log_softmax ----------------
__global__ void k_gather10_final(const float* __restrict__ hg, const int* __restrict__ rowptr,
                                 const int* __restrict__ adj, const float* __restrict__ dinv,
                                 const float* __restrict__ bend, float* __restrict__ out, int N) {
  int t = blockIdx.x * 256 + threadIdx.x;
  int n = t >> 4, j = t & 15;
  if (n >= N) return;
  float s = 0.f;
  if (j < C_OUT) {
    int beg = rowptr[n], end = rowptr[n + 1];
    s = hg[(size_t)n * 16 + j];  // self-loop
    int k = beg;
    for (; k + 4 <= end; k += 4) {
      int s0 = adj[k], s1 = adj[k + 1], s2 = adj[k + 2], s3 = adj[k + 3];
      float a = hg[(size_t)s0 * 16 + j];
      float b = hg[(size_t)s1 * 16 + j];
      float c = hg[(size_t)s2 * 16 + j];
      float d = hg[(size_t)s3 * 16 + j];
      s += (a + b) + (c + d);
    }
    for (; k < end; ++k) s += hg[(size_t)adj[k] * 16 + j];
  }
  float v = (j < C_OUT) ? fmaf(s, dinv[n], bend[j]) : -INFINITY;
  float mx = v;
  #pragma unroll
  for (int w = 8; w; w >>= 1) mx = fmaxf(mx, __shfl_xor(mx, w, 16));
  float e = (j < C_OUT) ? __expf(v - mx) : 0.f;
  float ss = e;
  #pragma unroll
  for (int w = 8; w; w >>= 1) ss += __shfl_xor(ss, w, 16);
  if (j < C_OUT) out[(size_t)n * C_OUT + j] = v - (__logf(ss) + mx);
}

extern "C" void kernel_launch(void* const* d_in, const int* in_sizes, int n_in,
                              void* d_out, int out_size, void* d_ws, size_t ws_size,
                              hipStream_t stream) {
  // inputs: 0=x1 1=x2 2=W1 3=b1 4=W_end 5=b_end 6=edge_index1 7=edge_index2 8=skip
  // x1 / edge_index1 / skip are dead w.r.t. the returned output.
  const float* x2   = (const float*)d_in[1];
  const float* W1   = (const float*)d_in[2];
  const float* b1   = (const float*)d_in[3];
  const float* Wend = (const float*)d_in[4];
  const float* bend = (const float*)d_in[5];
  const int*   ei2  = (const int*)d_in[7];
  const int N = in_sizes[1] / F_IN;
  const int E = in_sizes[7] / 2;
  const int* src = ei2;
  const int* dst = ei2 + E;

  char* base = (char*)d_ws;
  size_t off = 0;
  auto alloc = [&](size_t bytes) -> void* {
    void* p = (void*)(base + off);
    off += ((bytes + 255) / 256) * 256;
    return p;
  };
  int*   gcursor = (int*)  alloc((size_t)NB * 4);
  int*   gbbase  = (int*)  alloc(((size_t)NB + 1) * 4);
  int*   rowptr  = (int*)  alloc(((size_t)N + 1) * 4);
  float* dinv    = (float*)alloc((size_t)N * 4);
  int*   adj     = (int*)  alloc((size_t)E * 4);
  // region A: epart (NB<<CAP_SH ints = 16.8 MB) early; m+g (12.8 MB) later.
  char*  regA    = (char*) alloc(((size_t)NB << CAP_SH) * 4);
  int*   epart   = (int*)  regA;
  float* m       = (float*)regA;
  float* g       = (float*)(regA + (size_t)N * H_MID * 4);

  const dim3 blk(256);
  const int gEC = (E + CHUNK - 1) / CHUNK;   // 196
  const int gNB = (N + 255) >> BSH;          // 391
  const int gNF = ((N * 16) + 255) / 256;
  const int gG  = (N + 63) / 64;             // 1563

  hipLaunchKernelGGL(k_init,           dim3(1),   dim3(NB), 0, stream, gcursor);
  hipLaunchKernelGGL(k_partition2,     dim3(gEC), dim3(512), 0, stream, src, dst, gcursor, epart, E, gEC);
  hipLaunchKernelGGL(k_bscan,          dim3(1),   dim3(NB), 0, stream, gcursor, gbbase, rowptr, N, E);
  hipLaunchKernelGGL(k_place,          dim3(gNB), blk, 0, stream, epart, gbbase, gcursor, adj, rowptr, dinv, N);
  hipLaunchKernelGGL(k_gemv16,         dim3(gG),  blk, 0, stream, x2, W1, dinv, m, N);
  hipLaunchKernelGGL(k_gather16_mid,   dim3(gG),  blk, 0, stream, m, rowptr, adj, dinv, b1, Wend, g, N);
  hipLaunchKernelGGL(k_gather10_final, dim3(gNF), blk, 0, stream,
                     g, rowptr, adj, dinv, bend, (float*)d_out, N);
}